// Round 6
// baseline (733.799 us; speedup 1.0000x reference)
//
#include <hip/hip_runtime.h>

// Problem constants (from reference)
#define BATCH 16
#define HH 1024
#define WW 2048
#define HWPIX (HH * WW)            // 2,097,152 pixels per batch
#define NID 255                    // ids 101..355 -> index 0..254

#define THREADS 1024
#define SLICES 32                  // blocks per batch; 16*32 = 512 blocks = 2/CU
#define PIX_PER_BLOCK (HWPIX / SLICES)        // 65536 (32 rows of 2048)
#define ROWS_PER_BLOCK 32
#define ITERS (PIX_PER_BLOCK / (THREADS * 4)) // 16
#define NBLK (BATCH * SLICES)      // 512

typedef unsigned long long u64;
typedef unsigned u32;

// g_tab[block][id] — block-PRIVATE region (sole writer = owner block), zeroed
// by the owner at kernel start. One non-returning u64 global atomic per pixel.
// Packing, adversarially exact per (batch,slice,id):
//   [0,27)  sum_x      (worst: all 65536 slice px one id -> 32*2047*2048/2 = 67,076,096 < 2^27)
//   [27,47) sum_y_rel  (worst: 2048*(0+..+31) = 1,015,808 < 2^20)
//   [47,..) count      (worst: 65,536 < 2^17)

__global__ __launch_bounds__(THREADS) void accum_kernel(
    const float* __restrict__ logits, const int* __restrict__ label,
    u64* __restrict__ g_tab, double* __restrict__ g_exp)
{
    __shared__ double exp_lds[16];

    const int tid   = threadIdx.x;
    const int lane  = tid & 63;
    const int blk   = blockIdx.x;
    const int batch = blk >> 5;
    const int slice = blk & 31;

    u64* __restrict__ my = g_tab + (size_t)blk * NID;
    if (tid < NID) my[tid] = 0ull;     // private region: no cross-block hazard
    __syncthreads();                   // drains vmcnt -> zeros visible in L2

    const float4* lg4 = (const float4*)logits + (size_t)batch * (HWPIX / 4) + slice * (PIX_PER_BLOCK / 4);
    const int4*   lb4 = (const int4*)label   + (size_t)batch * (HWPIX / 4) + slice * (PIX_PER_BLOCK / 4);

    float es = 0.f;
#pragma unroll 4
    for (int i = 0; i < ITERS; ++i) {
        const int g = i * THREADS + tid;          // float4-group within slice
        const float4 f  = lg4[g];
        const int4   lb = lb4[g];
        es += __expf(f.x) + __expf(f.y) + __expf(f.z) + __expf(f.w);
        const int p0 = g << 2;                    // pixel index within slice
        const int yr = p0 >> 11;                  // local row (0..31)
        const int x0 = p0 & 2047;
        const u64 base = ((u64)1 << 47) | ((u64)yr << 27);
        // fire-and-forget u64 atomics; contention only within this block
        if (lb.x > 100) atomicAdd(&my[lb.x - 101], base | (u64)(x0 + 0));
        if (lb.y > 100) atomicAdd(&my[lb.y - 101], base | (u64)(x0 + 1));
        if (lb.z > 100) atomicAdd(&my[lb.z - 101], base | (u64)(x0 + 2));
        if (lb.w > 100) atomicAdd(&my[lb.w - 101], base | (u64)(x0 + 3));
    }

    // exp partial: wave shuffle reduce -> LDS -> ONE plain f64 store per block
    for (int off = 32; off > 0; off >>= 1) es += __shfl_down(es, off, 64);
    if (lane == 0) exp_lds[tid >> 6] = (double)es;
    __syncthreads();
    if (tid == 0) {
        double t = 0.0;
        for (int w = 0; w < 16; ++w) t += exp_lds[w];
        g_exp[blk] = t;
    }
}

__global__ __launch_bounds__(256) void batch_kernel(
    const float* __restrict__ logits, const u64* __restrict__ g_tab,
    double* __restrict__ g_binst)
{
    const int b   = blockIdx.x;
    const int tid = threadIdx.x;
    float s = 0.f;
    if (tid < NID) {                   // id = 101 + tid
        u32 cnt = 0, sx = 0, sy = 0;
        for (int sl = 0; sl < SLICES; ++sl) {
            const u64 v = g_tab[((size_t)b * SLICES + sl) * NID + tid];
            const u32 c = (u32)(v >> 47);
            cnt += c;
            sx  += (u32)(v & 0x7FFFFFFu);
            sy  += (u32)((v >> 27) & 0xFFFFFu) + (u32)(sl * ROWS_PER_BLOCK) * c;
        }
        if (cnt) {
            const float fc = (float)cnt;
            // identical f32 divide + truncation as the reference
            const int cx = (int)((float)sx / fc);
            const int cy = (int)((float)sy / fc);
            s = logits[(size_t)b * HWPIX + (size_t)cy * WW + cx];
        }
    }
    __shared__ float red[256];
    red[tid] = s;
    __syncthreads();
    for (int off = 128; off > 0; off >>= 1) {
        if (tid < off) red[tid] += red[tid + off];
        __syncthreads();
    }
    if (tid == 0) g_binst[b] = (double)red[0];
}

__global__ __launch_bounds__(256) void final_kernel(
    const double* __restrict__ g_exp, const double* __restrict__ g_binst,
    float* __restrict__ out)
{
    __shared__ double red[256];
    const int tid = threadIdx.x;
    red[tid] = g_exp[tid] + g_exp[tid + 256];
    __syncthreads();
    for (int off = 128; off > 0; off >>= 1) {
        if (tid < off) red[tid] += red[tid + off];
        __syncthreads();
    }
    if (tid == 0) {
        double inst = 0.0;
        for (int b = 0; b < BATCH; ++b) inst += g_binst[b];
        const double int_loss = red[0] / (double)((double)BATCH * (double)HWPIX);
        out[0] = (float)(int_loss - inst / (double)BATCH);
    }
}

extern "C" void kernel_launch(void* const* d_in, const int* in_sizes, int n_in,
                              void* d_out, int out_size, void* d_ws, size_t ws_size,
                              hipStream_t stream) {
    const float* logits = (const float*)d_in[0];
    const int*   label  = (const int*)d_in[1];
    float* out = (float*)d_out;

    u64*    g_tab   = (u64*)d_ws;                              // 512*255*8 = 1,044,480 B
    double* g_exp   = (double*)((char*)d_ws + (size_t)NBLK * NID * sizeof(u64));
    double* g_binst = g_exp + NBLK;                            // +4096 B, then 128 B

    // no memset needed: every workspace word is written each call before use
    accum_kernel<<<NBLK, THREADS, 0, stream>>>(logits, label, g_tab, g_exp);
    batch_kernel<<<BATCH, 256, 0, stream>>>(logits, g_tab, g_binst);
    final_kernel<<<1, 256, 0, stream>>>(g_exp, g_binst, out);
}

// Round 7
// 55.182 us; speedup vs baseline: 13.2979x; 13.2979x over previous
//
#include <hip/hip_runtime.h>

// Problem constants (from reference)
#define BATCH 16
#define HH 1024
#define WW 2048
#define HWPIX (HH * WW)            // 2,097,152 pixels per batch
#define NID 255                    // ids 101..355 -> index 0..254

#define THREADS 1024
#define SLICES 32                  // blocks per batch; 16*32 = 512 blocks = 2/CU
#define PIX_PER_BLOCK (HWPIX / SLICES)        // 65536 (32 rows of 2048)
#define ROWS_PER_BLOCK 32
#define ITERS (PIX_PER_BLOCK / (THREADS * 4)) // 16
#define NCOL 32                    // u64 columns per id (lane-pair private)
#define NBLK (BATCH * SLICES)      // 512
#define PSTR 13                    // flush-part stride (bank-friendly)

typedef unsigned long long u64;
typedef unsigned u32;

// Cell u64 per (id, lane-pair): exposure <= 2 lanes * 64 px = 128 px.
//   [0,24)  sum_x      (max 128*2047 = 262,016 < 2^24)
//   [24,40) sum_y_rel  (max 128*31   = 3,968   < 2^16)
//   [40,..) count      (max 128)
// Overflow-free for ANY data; same-address only when paired lanes share an id.

__global__ __launch_bounds__(THREADS) void accum_kernel(
    const float* __restrict__ logits, const int* __restrict__ label,
    u32* __restrict__ g_cnt, u32* __restrict__ g_sx, u32* __restrict__ g_sy,
    double* __restrict__ g_bexp_part)
{
    __shared__ u64 table[NID * NCOL];      // 65,280 B
    __shared__ u32 part[NID * PSTR];       // 13,260 B
    __shared__ double exp_lds[16];

    const int tid  = threadIdx.x;
    const int lane = tid & 63;
    const int col  = lane >> 1;            // lane-pair column
    const int blk   = blockIdx.x;
    const int batch = blk >> 5;
    const int slice = blk & 31;

    for (int i = tid; i < NID * NCOL; i += THREADS) table[i] = 0ull;
    __syncthreads();

    const float4* lg4 = (const float4*)logits + (size_t)batch * (HWPIX / 4) + slice * (PIX_PER_BLOCK / 4);
    const int4*   lb4 = (const int4*)label   + (size_t)batch * (HWPIX / 4) + slice * (PIX_PER_BLOCK / 4);

    float es = 0.f;
#pragma unroll 4
    for (int i = 0; i < ITERS; ++i) {
        const int g = i * THREADS + tid;          // float4-group within slice
        const float4 f  = lg4[g];
        const int4   lb = lb4[g];
        es += __expf(f.x) + __expf(f.y) + __expf(f.z) + __expf(f.w);
        const int p0 = g << 2;                    // pixel index within slice
        const int yr = p0 >> 11;                  // local row (0..31)
        const int x0 = p0 & 2047;
        const u64 base = ((u64)1 << 40) | ((u64)yr << 24);
        if (lb.x > 100) atomicAdd(&table[(lb.x - 101) * NCOL + col], base | (u64)(x0 + 0));
        if (lb.y > 100) atomicAdd(&table[(lb.y - 101) * NCOL + col], base | (u64)(x0 + 1));
        if (lb.z > 100) atomicAdd(&table[(lb.z - 101) * NCOL + col], base | (u64)(x0 + 2));
        if (lb.w > 100) atomicAdd(&table[(lb.w - 101) * NCOL + col], base | (u64)(x0 + 3));
    }

    // exp partial: wave shuffle reduce -> LDS
    for (int off = 32; off > 0; off >>= 1) es += __shfl_down(es, off, 64);
    if (lane == 0) exp_lds[tid >> 6] = (double)es;
    __syncthreads();

    // flush stage A: 4 threads per id, 8 u64 cells each -> LDS partials
    {
        const int fid  = tid >> 2;
        const int fsub = tid & 3;
        if (fid < NID) {
            u32 cnt_a = 0, sx_a = 0, syr_a = 0;
            const u64* cp = &table[fid * NCOL + fsub * 8];
#pragma unroll
            for (int j = 0; j < 8; ++j) {
                const u64 v = cp[j];
                cnt_a += (u32)(v >> 40);
                syr_a += (u32)((v >> 24) & 0xFFFFu);
                sx_a  += (u32)(v & 0xFFFFFFu);
            }
            part[fid * PSTR + fsub * 3 + 0] = cnt_a;
            part[fid * PSTR + fsub * 3 + 1] = sx_a;
            part[fid * PSTR + fsub * 3 + 2] = syr_a;
        }
    }
    __syncthreads();

    // exp: block partial -> ONE plain f64 store (block-private, no memset)
    if (tid == 0) {
        double t = 0.0;
        for (int w = 0; w < 16; ++w) t += exp_lds[w];
        g_bexp_part[blk] = t;
    }

    // flush stage B: one thread per id, plain stores (write ALL ids incl. zero)
    if (tid < NID) {
        u32 cnt_t = 0, sx_t = 0, syr_t = 0;
        for (int q = 0; q < 4; ++q) {
            cnt_t += part[tid * PSTR + q * 3 + 0];
            sx_t  += part[tid * PSTR + q * 3 + 1];
            syr_t += part[tid * PSTR + q * 3 + 2];
        }
        const size_t o = (size_t)blk * NID + tid;
        g_cnt[o] = cnt_t;
        g_sx [o] = sx_t;
        g_sy [o] = syr_t + (u32)(slice * ROWS_PER_BLOCK) * cnt_t;
    }
}

__global__ __launch_bounds__(256) void batch_kernel(
    const float* __restrict__ logits, const u32* __restrict__ g_cnt,
    const u32* __restrict__ g_sx, const u32* __restrict__ g_sy,
    const double* __restrict__ g_bexp_part,
    float* __restrict__ g_binst, double* __restrict__ g_bexp)
{
    const int b   = blockIdx.x;
    const int tid = threadIdx.x;

    // exp: combine this batch's 32 block partials in wave 0
    if (tid < 64) {
        double e = (tid < SLICES) ? g_bexp_part[b * SLICES + tid] : 0.0;
        for (int off = 32; off > 0; off >>= 1) e += __shfl_down(e, off, 64);
        if (tid == 0) g_bexp[b] = e;
    }

    float s = 0.f;
    if (tid < NID) {                   // id = 101 + tid
        u32 cnt = 0, sx = 0, sy = 0;
        for (int sl = 0; sl < SLICES; ++sl) {
            const size_t o = ((size_t)b * SLICES + sl) * NID + tid;  // coalesced over tid
            cnt += g_cnt[o];
            sx  += g_sx [o];
            sy  += g_sy [o];
        }
        if (cnt) {
            const float fc = (float)cnt;
            // identical f32 divide + truncation as the reference
            const int cx = (int)((float)sx / fc);
            const int cy = (int)((float)sy / fc);
            s = logits[(size_t)b * HWPIX + (size_t)cy * WW + cx];
        }
    }
    __shared__ float red[256];
    red[tid] = s;
    __syncthreads();
    for (int off = 128; off > 0; off >>= 1) {
        if (tid < off) red[tid] += red[tid + off];
        __syncthreads();
    }
    if (tid == 0) g_binst[b] = red[0];
}

__global__ __launch_bounds__(64) void final_kernel(
    const double* __restrict__ g_bexp, const float* __restrict__ g_binst,
    float* __restrict__ out)
{
    const int tid = threadIdx.x;
    double e = (tid < BATCH) ? g_bexp[tid] : 0.0;
    double i = (tid < BATCH) ? (double)g_binst[tid] : 0.0;
    for (int off = 32; off > 0; off >>= 1) {
        e += __shfl_down(e, off, 64);
        i += __shfl_down(i, off, 64);
    }
    if (tid == 0) {
        const double int_loss = e / (double)((double)BATCH * (double)HWPIX);
        out[0] = (float)(int_loss - i / (double)BATCH);
    }
}

extern "C" void kernel_launch(void* const* d_in, const int* in_sizes, int n_in,
                              void* d_out, int out_size, void* d_ws, size_t ws_size,
                              hipStream_t stream) {
    const float* logits = (const float*)d_in[0];
    const int*   label  = (const int*)d_in[1];
    float* out = (float*)d_out;

    // workspace layout (all regions fully rewritten every call -> no memset)
    u32*    g_cnt       = (u32*)d_ws;                       // 512*255 u32
    u32*    g_sx        = g_cnt + (size_t)NBLK * NID;
    u32*    g_sy        = g_sx  + (size_t)NBLK * NID;
    double* g_bexp_part = (double*)(g_sy + (size_t)NBLK * NID);   // 512 f64 (8-aligned)
    double* g_bexp      = g_bexp_part + NBLK;               // 16 f64
    float*  g_binst     = (float*)(g_bexp + BATCH);         // 16 f32

    accum_kernel<<<NBLK, THREADS, 0, stream>>>(logits, label, g_cnt, g_sx, g_sy, g_bexp_part);
    batch_kernel<<<BATCH, 256, 0, stream>>>(logits, g_cnt, g_sx, g_sy, g_bexp_part, g_binst, g_bexp);
    final_kernel<<<1, 64, 0, stream>>>(g_bexp, g_binst, out);
}